// Round 8
// baseline (24890.384 us; speedup 1.0000x reference)
//
#include <hip/hip_runtime.h>
#include <stdint.h>

// ---------------------------------------------------------------------------
// SimpleRNN: bidirectional LSTM encoder (S=256) + autoregressive decoder (T=128)
// B=128, D=256, H=1024. Persistent kernels, fence-free flag grid barriers.
// R8: per-XCD L2-resident h mirror. Grouping by hardware XCC_ID (s_getreg).
// After each step's grid barrier, each XCD cooperatively copies the h panel
// (coherent read from L3) into its private scratch (plain stores -> own L2);
// consumers stage h with sc0 (L1-bypass, L2-served) global_load_lds.
// 3-term split-bf16 MFMA (Wh*Ah + Wh*Al + Wl*Ah), f32 accum/gates.
// ---------------------------------------------------------------------------

typedef __attribute__((ext_vector_type(8))) short bfx8;
typedef __attribute__((ext_vector_type(4))) float f32x4;
typedef __attribute__((ext_vector_type(4))) unsigned short u16x4;
typedef unsigned short ushort_t;
typedef unsigned long long u64;

#define NWG 256
#define MFMA(a,b,c) __builtin_amdgcn_mfma_f32_16x16x32_bf16((a),(b),(c),0,0,0)
#define WAITVM(N) { asm volatile("s_waitcnt vmcnt(" #N ")" ::: "memory"); __builtin_amdgcn_sched_barrier(0); }
#define WAITLG(N) { asm volatile("s_waitcnt lgkmcnt(" #N ")" ::: "memory"); __builtin_amdgcn_sched_barrier(0); }
#define SBAR()    { __builtin_amdgcn_s_barrier(); __builtin_amdgcn_sched_barrier(0); }

__device__ __forceinline__ unsigned short f2bf(float f){
  unsigned u = __float_as_uint(f);
  u += 0x7FFFu + ((u >> 16) & 1u);          // round-to-nearest-even
  return (unsigned short)(u >> 16);
}
__device__ __forceinline__ float bf2f(unsigned short h){
  return __uint_as_float(((unsigned)h) << 16);
}
__device__ __forceinline__ float sigm(float x){ return 1.f/(1.f + __expf(-x)); }
__device__ __forceinline__ float tanh_(float x){ return 1.f - 2.f/(__expf(2.f*x) + 1.f); }

// plain (L1+L2 cached) async global->LDS: immutable weights
__device__ __forceinline__ void stage16(const void* g, void* l){
  __builtin_amdgcn_global_load_lds((const __attribute__((address_space(1))) void*)g,
                                   (__attribute__((address_space(3))) void*)l,
                                   16, 0, 0);
}
// agent-coherent (SC0|SC1 = 0x11, L3-served): mutable cross-XCD data
__device__ __forceinline__ void stage16c(const void* g, void* l){
  __builtin_amdgcn_global_load_lds((const __attribute__((address_space(1))) void*)g,
                                   (__attribute__((address_space(3))) void*)l,
                                   16, 0, 0x11);
}
// sc0-only (L1-bypass, L2-served): per-XCD scratch reads (writer L2 == reader L2)
__device__ __forceinline__ void stage16s(const void* g, void* l){
  __builtin_amdgcn_global_load_lds((const __attribute__((address_space(1))) void*)g,
                                   (__attribute__((address_space(3))) void*)l,
                                   16, 0, 0x1);
}

// coherent 16B load (2 x u64 agent-relaxed atomics)
__device__ __forceinline__ bfx8 ld16c(const ushort_t* p){
  const u64* q = (const u64*)p;
  u64 a = __hip_atomic_load(q,     __ATOMIC_RELAXED, __HIP_MEMORY_SCOPE_AGENT);
  u64 b = __hip_atomic_load(q + 1, __ATOMIC_RELAXED, __HIP_MEMORY_SCOPE_AGENT);
  union { u64 u[2]; bfx8 v; } x; x.u[0] = a; x.u[1] = b; return x.v;
}
__device__ __forceinline__ void sth2(ushort_t* p, unsigned short v){
  __hip_atomic_store(p, v, __ATOMIC_RELAXED, __HIP_MEMORY_SCOPE_AGENT);
}

// two f32x4 (8 consecutive f32) -> hi/lo bf16 planes
__device__ __forceinline__ void cvt2(const f32x4& a, const f32x4& b, bfx8& hi, bfx8& lo){
#pragma unroll
  for (int j = 0; j < 4; ++j){
    unsigned short h0 = f2bf(a[j]);
    unsigned short h1 = f2bf(b[j]);
    hi[j]   = (short)h0; lo[j]   = (short)f2bf(a[j] - bf2f(h0));
    hi[4+j] = (short)h1; lo[4+j] = (short)f2bf(b[j] - bf2f(h1));
  }
}

// ---------------------------------------------------------------------------
// Fence-free grid barrier (flag store + wave0 scan). No cache invalidation.
// ---------------------------------------------------------------------------
__device__ __forceinline__ void bar(unsigned* flags, int nflags, int me, unsigned gen){
  __syncthreads();                       // drains vmcnt(0): all stores done
  if (threadIdx.x == 0)
    __hip_atomic_store(&flags[me], gen, __ATOMIC_RELAXED, __HIP_MEMORY_SCOPE_AGENT);
  if (threadIdx.x < 64){
    const int l = threadIdx.x;
    for (;;){
      unsigned mn = 0xFFFFFFFFu;
      for (int o = l; o < nflags; o += 64){
        unsigned v = __hip_atomic_load(&flags[o], __ATOMIC_RELAXED, __HIP_MEMORY_SCOPE_AGENT);
        mn = mn < v ? mn : v;
      }
      if (__all((int)(mn >= gen))) break;
      __builtin_amdgcn_s_sleep(1);
    }
  }
  __syncthreads();
}

// ---------------------------------------------------------------------------
// XCD registration (hardware XCC_ID) + per-XCD barrier.
// ---------------------------------------------------------------------------
__device__ __forceinline__ void xreg(unsigned* regc, int grp, int& xcc, int& rank){
  __shared__ unsigned s0, s1;
  if (threadIdx.x == 0){
    unsigned x;
    asm volatile("s_getreg_b32 %0, hwreg(HW_REG_XCC_ID)" : "=s"(x));
    x &= 7u;
    s0 = x;
    s1 = atomicAdd(&regc[(grp*8 + (int)x)*16], 1u);
  }
  __syncthreads();
  xcc = (int)s0; rank = (int)s1;
}
__device__ __forceinline__ int xnmem(unsigned* regc, int grp, int xcc){
  __shared__ unsigned s;
  if (threadIdx.x == 0)
    s = __hip_atomic_load(&regc[(grp*8 + xcc)*16], __ATOMIC_RELAXED, __HIP_MEMORY_SCOPE_AGENT);
  __syncthreads();
  return (int)s;
}
__device__ __forceinline__ void xbar(unsigned* arr, unsigned* flag, int nmem, unsigned gen){
  __syncthreads();                       // copier's plain stores are in own L2
  if (threadIdx.x == 0){
    unsigned a = atomicAdd(arr, 1u);
    if (a == gen*(unsigned)nmem - 1u)
      __hip_atomic_store(flag, gen, __ATOMIC_RELAXED, __HIP_MEMORY_SCOPE_AGENT);
    while (__hip_atomic_load(flag, __ATOMIC_RELAXED, __HIP_MEMORY_SCOPE_AGENT) < gen)
      __builtin_amdgcn_s_sleep(1);
  }
  __syncthreads();
}

// Cooperative copy of the h panel into this XCD's scratch (plain stores).
// Half-panel (one dir, 16384 x 16B units) or full panel (32768 units).
__device__ __forceinline__ void xcopy_half(
    const ushort_t* Hs, const ushort_t* Ls, ushort_t* Hd, ushort_t* Ld,
    int dir, int rank, int nmem){
  for (int u = rank*256 + (int)threadIdx.x; u < 16384; u += nmem*256){
    const size_t o = (size_t)(u >> 7)*2048 + (size_t)dir*1024 + (size_t)(u & 127)*8;
    const u64* s1 = (const u64*)(Hs + o);
    const u64* s2 = (const u64*)(Ls + o);
    u64 a = __hip_atomic_load(s1,     __ATOMIC_RELAXED, __HIP_MEMORY_SCOPE_AGENT);
    u64 b = __hip_atomic_load(s1 + 1, __ATOMIC_RELAXED, __HIP_MEMORY_SCOPE_AGENT);
    u64 c = __hip_atomic_load(s2,     __ATOMIC_RELAXED, __HIP_MEMORY_SCOPE_AGENT);
    u64 d = __hip_atomic_load(s2 + 1, __ATOMIC_RELAXED, __HIP_MEMORY_SCOPE_AGENT);
    ((u64*)(Hd + o))[0] = a; ((u64*)(Hd + o))[1] = b;
    ((u64*)(Ld + o))[0] = c; ((u64*)(Ld + o))[1] = d;
  }
}
__device__ __forceinline__ void xcopy_full(
    const ushort_t* Hs, const ushort_t* Ls, ushort_t* Hd, ushort_t* Ld,
    int rank, int nmem){
  for (int u = rank*256 + (int)threadIdx.x; u < 32768; u += nmem*256){
    const size_t o = (size_t)u*8;
    const u64* s1 = (const u64*)(Hs + o);
    const u64* s2 = (const u64*)(Ls + o);
    u64 a = __hip_atomic_load(s1,     __ATOMIC_RELAXED, __HIP_MEMORY_SCOPE_AGENT);
    u64 b = __hip_atomic_load(s1 + 1, __ATOMIC_RELAXED, __HIP_MEMORY_SCOPE_AGENT);
    u64 c = __hip_atomic_load(s2,     __ATOMIC_RELAXED, __HIP_MEMORY_SCOPE_AGENT);
    u64 d = __hip_atomic_load(s2 + 1, __ATOMIC_RELAXED, __HIP_MEMORY_SCOPE_AGENT);
    ((u64*)(Hd + o))[0] = a; ((u64*)(Hd + o))[1] = b;
    ((u64*)(Ld + o))[0] = c; ((u64*)(Ld + o))[1] = d;
  }
}

struct Frags { bfx8 awh0, awh1, awl0, awl1, bh0, bh1, bl0, bl1; };

// ---------------------------------------------------------------------------
// One LSTM cell step. Phase 1 (k<256): register-staged. Phase 2: depth-3
// global_load_lds ring, counted vmcnt. h source: COH=1 -> global (0x11),
// COH=0 -> per-XCD scratch (sc0). Weight planes plain (L2-cached).
// ---------------------------------------------------------------------------
template<int ENC, int COH>
__device__ __forceinline__ void cell_step(
    const float*    __restrict__ Wih,   // [4096][256] f32 original (this dir)
    const ushort_t* __restrict__ WhH,   // [4096][1024] bf16 hi (this dir)
    const ushort_t* __restrict__ WhL,   // lo
    const float*    __restrict__ bias,  // [4096] f32 (original order)
    const float*    __restrict__ xsl,   // ENC: x + tt*256 (row stride 65536)
    const ushort_t* __restrict__ iph,   // DEC: [128][256] hi
    const ushort_t* __restrict__ ipl,   // DEC: lo
    const ushort_t* __restrict__ hh,    // h hi source (+dir*1024), stride 2048
    const ushort_t* __restrict__ hl,    // h lo source
    ushort_t* __restrict__ outh, ushort_t* __restrict__ outl,
    float (&creg)[2][2],
    int r0, int n0, int b0, ushort_t* LDS)
{
  const int tid  = threadIdx.x;
  const int lane = tid & 63;
  const int wv   = tid >> 6;
  const int wm   = wv >> 1, wn = wv & 1;
  const int lr   = tid >> 3;               // phase-1 staging row 0..31
  const int lc   = tid & 7;
  const int cb   = lane >> 4;
  const int fr   = lane & 15;
  const int sc8  = lc ^ (lr & 7);          // phase-1 pre-swizzled source chunk
  const int sx   = fr & 7;
  const int rwa0 = wm*32 + fr, rwa1 = rwa0 + 16;
  const int rwb0 = wn*32 + fr, rwb1 = rwb0 + 16;

  // ---- phase-1 source pointers (rows r0+lr, r0+32+lr; gate-interleaved) ----
  const int ra = r0 + lr, rb = ra + 32;
  const float* wih0 = Wih + (size_t)((ra & 3)*1024 + (ra >> 2))*256 + sc8*8;
  const float* wih1 = Wih + (size_t)((rb & 3)*1024 + (rb >> 2))*256 + sc8*8;
  const float *xs0 = nullptr, *xs1 = nullptr;
  const ushort_t *ih0 = nullptr, *ih1 = nullptr, *il0 = nullptr, *il1 = nullptr;
  if (ENC){
    xs0 = xsl + (size_t)(b0 + lr)*65536 + sc8*8;
    xs1 = xs0 + (size_t)32*65536;
  } else {
    ih0 = iph + (size_t)(b0 + lr)*256 + sc8*8;  ih1 = ih0 + 32*256;
    il0 = ipl + (size_t)(b0 + lr)*256 + sc8*8;  il1 = il0 + 32*256;
  }

  // ---- phase-2 staging bases: wave wv stages plane wv ----
  const ushort_t* sb; size_t sstr; int srow0;
  if      (wv == 0){ sb = WhH; sstr = 1024; srow0 = r0; }
  else if (wv == 1){ sb = WhL; sstr = 1024; srow0 = r0; }
  else if (wv == 2){ sb = hh;  sstr = 2048; srow0 = b0; }
  else             { sb = hl;  sstr = 2048; srow0 = b0; }
  const int srw = lane >> 3;
  const int sg  = (lane & 7) ^ srw;        // swizzled source granule
  const ushort_t* pj[8];
#pragma unroll
  for (int j = 0; j < 8; ++j)
    pj[j] = sb + (size_t)(srow0 + j*8 + srw)*sstr + sg*8;
  ushort_t* ldsb[3];
#pragma unroll
  for (int bp = 0; bp < 3; ++bp)
    ldsb[bp] = LDS + 16384 + bp*16384 + wv*4096;

  auto ISSUE = [&](int c, int bp){
    const int ko = (c - 4)*64;
    if (wv < 2){
#pragma unroll
      for (int j = 0; j < 8; ++j)
        stage16(pj[j] + ko, ldsb[bp] + j*512);          // weights: L2-cached
    } else if (COH){
#pragma unroll
      for (int j = 0; j < 8; ++j)
        stage16c(pj[j] + ko, ldsb[bp] + j*512);         // h: global coherent
    } else {
#pragma unroll
      for (int j = 0; j < 8; ++j)
        stage16s(pj[j] + ko, ldsb[bp] + j*512);         // h: XCD scratch (L2)
    }
  };

  f32x4 acc[2][2] = {};
  auto rdf = [&](const ushort_t* buf, int ks, Frags& f){
    const int ga = (((ks << 2) + cb) ^ sx) << 3;
    f.awh0 = *(const bfx8*)(buf +         rwa0*64 + ga);
    f.awh1 = *(const bfx8*)(buf +         rwa1*64 + ga);
    f.awl0 = *(const bfx8*)(buf + 4096  + rwa0*64 + ga);
    f.awl1 = *(const bfx8*)(buf + 4096  + rwa1*64 + ga);
    f.bh0  = *(const bfx8*)(buf + 8192  + rwb0*64 + ga);
    f.bh1  = *(const bfx8*)(buf + 8192  + rwb1*64 + ga);
    f.bl0  = *(const bfx8*)(buf + 12288 + rwb0*64 + ga);
    f.bl1  = *(const bfx8*)(buf + 12288 + rwb1*64 + ga);
  };
  auto mm12 = [&](const Frags& f){
    acc[0][0] = MFMA(f.awh0, f.bh0, acc[0][0]);
    acc[0][0] = MFMA(f.awh0, f.bl0, acc[0][0]);
    acc[0][0] = MFMA(f.awl0, f.bh0, acc[0][0]);
    acc[0][1] = MFMA(f.awh0, f.bh1, acc[0][1]);
    acc[0][1] = MFMA(f.awh0, f.bl1, acc[0][1]);
    acc[0][1] = MFMA(f.awl0, f.bh1, acc[0][1]);
    acc[1][0] = MFMA(f.awh1, f.bh0, acc[1][0]);
    acc[1][0] = MFMA(f.awh1, f.bl0, acc[1][0]);
    acc[1][0] = MFMA(f.awl1, f.bh0, acc[1][0]);
    acc[1][1] = MFMA(f.awh1, f.bh1, acc[1][1]);
    acc[1][1] = MFMA(f.awh1, f.bl1, acc[1][1]);
    acc[1][1] = MFMA(f.awl1, f.bh1, acc[1][1]);
  };

  // ---- phase-1 raw loads / cvt ----
  f32x4 rw0a, rw0b, rw1a, rw1b, rxa0, rxb0, rxa1, rxb1;
  bfx8 cwh0, cwh1, cwl0, cwl1, cah0, cah1, cal0, cal1;
  auto LOADRAW = [&](int kc){
    rw0a = *(const f32x4*)(wih0 + kc);  rw0b = *(const f32x4*)(wih0 + kc + 4);
    rw1a = *(const f32x4*)(wih1 + kc);  rw1b = *(const f32x4*)(wih1 + kc + 4);
    if (ENC){
      rxa0 = *(const f32x4*)(xs0 + kc); rxb0 = *(const f32x4*)(xs0 + kc + 4);
      rxa1 = *(const f32x4*)(xs1 + kc); rxb1 = *(const f32x4*)(xs1 + kc + 4);
    } else {
      cah0 = ld16c(ih0 + kc);  cah1 = ld16c(ih1 + kc);   // coherent inp
      cal0 = ld16c(il0 + kc);  cal1 = ld16c(il1 + kc);
    }
  };
  auto CVT = [&](){
    cvt2(rw0a, rw0b, cwh0, cwl0);
    cvt2(rw1a, rw1b, cwh1, cwl1);
    if (ENC){ cvt2(rxa0, rxb0, cah0, cal0); cvt2(rxa1, rxb1, cah1, cal1); }
  };

  LOADRAW(0);
  ISSUE(4, 0); ISSUE(5, 1); ISSUE(6, 2);     // phase-2 prologue (24 in flight)
  CVT();

  // ---- phase 1: chunks 0..3, register-staged into P1, raw barriers ----
  for (int c = 0; c < 4; ++c){
    *(bfx8*)(LDS +         lr    *64 + lc*8) = cwh0;
    *(bfx8*)(LDS +        (lr+32)*64 + lc*8) = cwh1;
    *(bfx8*)(LDS + 4096 +  lr    *64 + lc*8) = cwl0;
    *(bfx8*)(LDS + 4096 + (lr+32)*64 + lc*8) = cwl1;
    *(bfx8*)(LDS + 8192 +  lr    *64 + lc*8) = cah0;
    *(bfx8*)(LDS + 8192 + (lr+32)*64 + lc*8) = cah1;
    *(bfx8*)(LDS + 12288 + lr    *64 + lc*8) = cal0;
    *(bfx8*)(LDS + 12288 +(lr+32)*64 + lc*8) = cal1;
    WAITLG(0); SBAR();
    if (c < 3) LOADRAW((c + 1)*64);
    Frags f0, f1;
    rdf(LDS, 0, f0);
    rdf(LDS, 1, f1);
    WAITLG(8);
    mm12(f0);
    WAITLG(0); SBAR();
    if (c < 3) CVT();
    mm12(f1);
  }

  // ---- phase 2: chunks 4..19, depth-3 ring, counted vmcnt ----
  int bi = 0;
  for (int i = 4; i <= 19; ++i){
    if (i < 18)      { WAITVM(16); }
    else if (i == 18){ WAITVM(8); }
    else             { WAITVM(0); }
    SBAR();                                  // chunk i staged by all waves
    const ushort_t* buf = LDS + 16384 + bi*16384;
    Frags f0, f1;
    rdf(buf, 0, f0);
    rdf(buf, 1, f1);
    WAITLG(8);
    mm12(f0);
    WAITLG(0); SBAR();                       // all reads done -> buf free
    if (i <= 16) ISSUE(i + 3, bi);
    mm12(f1);
    bi = (bi == 2) ? 0 : bi + 1;
  }

  // ---- epilogue: gates -> c (regs), h -> global hi/lo planes (coherent) ----
#pragma unroll
  for (int m = 0; m < 2; ++m){
    const int n = n0 + wm*8 + m*4 + cb;
    const float bi_ = bias[n];
    const float bf_ = bias[1024 + n];
    const float bg_ = bias[2048 + n];
    const float bo_ = bias[3072 + n];
#pragma unroll
    for (int nb = 0; nb < 2; ++nb){
      const int b = b0 + wn*32 + nb*16 + fr;
      float gi = acc[m][nb][0] + bi_;
      float gf = acc[m][nb][1] + bf_;
      float gg = acc[m][nb][2] + bg_;
      float go = acc[m][nb][3] + bo_;
      float c_new = sigm(gf)*creg[m][nb] + sigm(gi)*tanh_(gg);
      float h_new = sigm(go)*tanh_(c_new);
      creg[m][nb] = c_new;
      unsigned short hi = f2bf(h_new);
      sth2(&outh[(size_t)b*2048 + n], hi);
      sth2(&outl[(size_t)b*2048 + n], f2bf(h_new - bf2f(hi)));
    }
  }
}

// ---------------------------------------------------------------------------
// MLP GEMM: 256 WGs = 16 d-tiles x 8 b-tiles x 2 K-halves; wave-private K=256
// strip staging. h from XCD scratch (sc0); weights plain. Partials coherent.
// ---------------------------------------------------------------------------
__device__ __forceinline__ void mlp_gemm(
    const ushort_t* __restrict__ hch, const ushort_t* __restrict__ hcl,
    const ushort_t* __restrict__ mWh, const ushort_t* __restrict__ mWl,
    float* __restrict__ Part, int wg, ushort_t* LDS)
{
  const int tid = threadIdx.x, lane = tid & 63, wv = tid >> 6;
  const int cb = lane >> 4, fr = lane & 15, sx = fr & 7;
  const int wgl = wg & 127, kh = wg >> 7;
  const int d0 = (wgl >> 3)*16, b0 = (wgl & 7)*16;
  const int kb = kh*1024 + wv*256;
  const int srw = lane >> 3, sg = (lane & 7) ^ srw;

  const ushort_t* ps[4] = { mWh, mWl, hch, hcl };
  const int pr0[4] = { d0, d0, b0, b0 };
  const ushort_t* pj[4][2];
#pragma unroll
  for (int p = 0; p < 4; ++p)
#pragma unroll
    for (int j = 0; j < 2; ++j)
      pj[p][j] = ps[p] + (size_t)(pr0[p] + j*8 + srw)*2048 + kb + sg*8;
  ushort_t* lb[3];
#pragma unroll
  for (int bp = 0; bp < 3; ++bp)
    lb[bp] = LDS + 16384 + (wv*3 + bp)*4096;

  auto ISSUE = [&](int c, int bp){
    const int ko = c*64;
#pragma unroll
    for (int p = 0; p < 4; ++p)
#pragma unroll
      for (int j = 0; j < 2; ++j){
        if (p < 2) stage16 (pj[p][j] + ko, lb[bp] + p*1024 + j*512);  // weights
        else       stage16s(pj[p][j] + ko, lb[bp] + p*1024 + j*512);  // scr h
      }
  };
  ISSUE(0, 0); ISSUE(1, 1); ISSUE(2, 2);

  f32x4 acc = {};
  int bp = 0;
  for (int c = 0; c < 4; ++c){
    if (c < 2)      { WAITVM(16); }
    else if (c == 2){ WAITVM(8); }
    else            { WAITVM(0); }
    const ushort_t* B = lb[bp];
    const int ga0 = ((cb) ^ sx) << 3;
    const int ga1 = ((4 + cb) ^ sx) << 3;
    bfx8 wh0 = *(const bfx8*)(B +        fr*64 + ga0);
    bfx8 wl0 = *(const bfx8*)(B + 1024 + fr*64 + ga0);
    bfx8 ah0 = *(const bfx8*)(B + 2048 + fr*64 + ga0);
    bfx8 al0 = *(const bfx8*)(B + 3072 + fr*64 + ga0);
    bfx8 wh1 = *(const bfx8*)(B +        fr*64 + ga1);
    bfx8 wl1 = *(const bfx8*)(B + 1024 + fr*64 + ga1);
    bfx8 ah1 = *(const bfx8*)(B + 2048 + fr*64 + ga1);
    bfx8 al1 = *(const bfx8*)(B + 3072 + fr*64 + ga1);
    WAITLG(0);
    if (c == 0) ISSUE(3, 0);
    acc = MFMA(wh0, ah0, acc); acc = MFMA(wh0, al0, acc); acc = MFMA(wl0, ah0, acc);
    acc = MFMA(wh1, ah1, acc); acc = MFMA(wh1, al1, acc); acc = MFMA(wl1, ah1, acc);
    bp = (bp == 2) ? 0 : bp + 1;
  }
  u64* P8 = (u64*)Part;
  const size_t idx = (((size_t)wgl*2 + kh)*4 + wv)*64 + lane;
  u64 a = ((u64)__float_as_uint(acc[1]) << 32) | __float_as_uint(acc[0]);
  u64 b = ((u64)__float_as_uint(acc[3]) << 32) | __float_as_uint(acc[2]);
  __hip_atomic_store(&P8[2*idx],     a, __ATOMIC_RELAXED, __HIP_MEMORY_SCOPE_AGENT);
  __hip_atomic_store(&P8[2*idx + 1], b, __ATOMIC_RELAXED, __HIP_MEMORY_SCOPE_AGENT);
}

// Combine partials: 128 WGs (wave 0 only), write dout + next input planes.
__device__ __forceinline__ void mlp_combine(
    const float* __restrict__ Part, const float* __restrict__ mb,
    float* __restrict__ dout,
    ushort_t* __restrict__ inph, ushort_t* __restrict__ inpl, int wg, int t)
{
  if (threadIdx.x >= 64) return;
  const int lane = threadIdx.x;
  const int d0 = (wg >> 3)*16, b0 = (wg & 7)*16;
  const int cb = lane >> 4, fr = lane & 15;
  const u64* P8 = (const u64*)Part;
  f32x4 s = {};
#pragma unroll
  for (int kh = 0; kh < 2; ++kh)
#pragma unroll
    for (int wv = 0; wv < 4; ++wv){
      const size_t idx = (((size_t)wg*2 + kh)*4 + wv)*64 + lane;
      u64 a = __hip_atomic_load(&P8[2*idx],     __ATOMIC_RELAXED, __HIP_MEMORY_SCOPE_AGENT);
      u64 b = __hip_atomic_load(&P8[2*idx + 1], __ATOMIC_RELAXED, __HIP_MEMORY_SCOPE_AGENT);
      s[0] += __uint_as_float((unsigned)a);
      s[1] += __uint_as_float((unsigned)(a >> 32));
      s[2] += __uint_as_float((unsigned)b);
      s[3] += __uint_as_float((unsigned)(b >> 32));
    }
  const int dr = d0 + cb*4, b = b0 + fr;
  s += *(const f32x4*)&mb[dr];
  *(f32x4*)&dout[((size_t)b*128 + t)*256 + dr] = s;
  u16x4 hv, lv;
#pragma unroll
  for (int j = 0; j < 4; ++j){
    hv[j] = f2bf(s[j]);
    lv[j] = f2bf(s[j] - bf2f(hv[j]));
  }
  union { u16x4 v; u64 u; } ch, cl; ch.v = hv; cl.v = lv;
  __hip_atomic_store((u64*)&inph[(size_t)b*256 + dr], ch.u, __ATOMIC_RELAXED, __HIP_MEMORY_SCOPE_AGENT);
  __hip_atomic_store((u64*)&inpl[(size_t)b*256 + dr], cl.u, __ATOMIC_RELAXED, __HIP_MEMORY_SCOPE_AGENT);
}

// WG -> (dir, rowgroup, b-half)
__device__ __forceinline__ void wg_decode(int wg, int& dir, int& r0, int& n0,
                                          int& b0, int& me){
  const int half = (wg >> 3) & 1;
  const int rgd  = (wg & 7) | ((wg >> 4) << 3);        // 0..127
  dir = rgd >> 6;
  const int rg = rgd & 63;
  r0 = rg * 64; n0 = rg * 16; b0 = half * 64;
  me = (rg << 1) | half;                               // 0..127 within dir
}

__global__ void __launch_bounds__(256) rnn_enc_kernel(
    const float* __restrict__ Wih_f, const float* __restrict__ b_f,
    const float* __restrict__ Wih_b, const float* __restrict__ b_b,
    const ushort_t* __restrict__ WhhH, const ushort_t* __restrict__ WhhL,
    const float* __restrict__ x,
    ushort_t* __restrict__ Hh, ushort_t* __restrict__ Hl,
    ushort_t* __restrict__ scrH, ushort_t* __restrict__ scrL,
    float* __restrict__ C, unsigned* flagsE,
    unsigned* eReg, unsigned* eArr, unsigned* eFlg)
{
  extern __shared__ ushort_t LDS[];
  int dir, r0, n0, b0, me;
  wg_decode(blockIdx.x, dir, r0, n0, b0, me);
  const float* Wih = dir ? Wih_b : Wih_f;
  const float* bia = dir ? b_b : b_f;
  const ushort_t* WhH = WhhH + (size_t)dir*4096*1024;
  const ushort_t* WhL = WhhL + (size_t)dir*4096*1024;
  unsigned* fl = flagsE + dir*128;

  int xcc, rank;
  xreg(eReg, dir, xcc, rank);
  bar(fl, 128, me, 1);                       // registration complete (per dir)
  const int nmem = xnmem(eReg, dir, xcc);
  const ushort_t* sH = scrH + (size_t)xcc*262144;
  const ushort_t* sL = scrL + (size_t)xcc*262144;
  unsigned* xa = eArr + (dir*8 + xcc)*16;
  unsigned* xf = eFlg + (dir*8 + xcc)*16;

  float creg[2][2] = {{0.f, 0.f}, {0.f, 0.f}};
  for (int t = 0; t < 256; ++t){
    const int tt = dir ? (255 - t) : t;
    const int rp = t & 1;
    cell_step<1,0>(Wih, WhH, WhL, bia,
                   x + (size_t)tt*256, nullptr, nullptr,
                   sH + dir*1024, sL + dir*1024,          // h from XCD scratch
                   Hh + (size_t)(rp^1)*262144 + dir*1024,
                   Hl + (size_t)(rp^1)*262144 + dir*1024,
                   creg, r0, n0, b0, LDS);
    bar(fl, 128, me, (unsigned)(t + 2));
    if (t < 255){
      xcopy_half(Hh + (size_t)(rp^1)*262144, Hl + (size_t)(rp^1)*262144,
                 (ushort_t*)sH, (ushort_t*)sL, dir, rank, nmem);
      xbar(xa, xf, nmem, (unsigned)(t + 1));
    }
  }
  // hand off c-state to decoder (cross-kernel boundary flushes)
  {
    const int lane = threadIdx.x & 63, wv = threadIdx.x >> 6;
    const int wm = wv >> 1, wn = wv & 1, cb = lane >> 4, fr = lane & 15;
    float* Cst = C + (size_t)dir*1024*128;
#pragma unroll
    for (int m = 0; m < 2; ++m)
#pragma unroll
      for (int nb = 0; nb < 2; ++nb){
        const int n = n0 + wm*8 + m*4 + cb;
        const int b = b0 + wn*32 + nb*16 + fr;
        Cst[n*128 + b] = creg[m][nb];
      }
  }
}

__global__ void __launch_bounds__(256) rnn_dec_kernel(
    const float* __restrict__ Wih_f, const float* __restrict__ b_f,
    const float* __restrict__ Wih_b, const float* __restrict__ b_b,
    const ushort_t* __restrict__ WhhH, const ushort_t* __restrict__ WhhL,
    const ushort_t* __restrict__ mWh, const ushort_t* __restrict__ mWl,
    const float* __restrict__ mb,
    ushort_t* __restrict__ Hh, ushort_t* __restrict__ Hl,
    ushort_t* __restrict__ scrH, ushort_t* __restrict__ scrL,
    float* __restrict__ C,
    ushort_t* __restrict__ inph, ushort_t* __restrict__ inpl,
    float* __restrict__ Part,
    float* __restrict__ dout, unsigned* flagsD,
    unsigned* dReg, unsigned* dArr, unsigned* dFlg)
{
  extern __shared__ ushort_t LDS[];
  const int wg = blockIdx.x;
  int dir, r0, n0, b0, me;
  wg_decode(wg, dir, r0, n0, b0, me);
  const float* Wih = dir ? Wih_b : Wih_f;
  const float* bia = dir ? b_b : b_f;
  const ushort_t* WhH = WhhH + (size_t)dir*4096*1024;
  const ushort_t* WhL = WhhL + (size_t)dir*4096*1024;

  int xcc, rank;
  xreg(dReg, 0, xcc, rank);
  bar(flagsD, 256, wg, 1);                   // registration complete
  const int nmem = xnmem(dReg, 0, xcc);
  const ushort_t* sH = scrH + (size_t)xcc*262144;
  const ushort_t* sL = scrL + (size_t)xcc*262144;
  unsigned* xa = dArr + xcc*16;
  unsigned* xf = dFlg + xcc*16;

  float creg[2][2];
  {
    const int lane = threadIdx.x & 63, wv = threadIdx.x >> 6;
    const int wm = wv >> 1, wn = wv & 1, cb = lane >> 4, fr = lane & 15;
    const float* Cst = C + (size_t)dir*1024*128;
#pragma unroll
    for (int m = 0; m < 2; ++m)
#pragma unroll
      for (int nb = 0; nb < 2; ++nb){
        const int n = n0 + wm*8 + m*4 + cb;
        const int b = b0 + wn*32 + nb*16 + fr;
        creg[m][nb] = Cst[n*128 + b];
      }
  }
  for (int t = 0; t < 128; ++t){
    const int rp = t & 1;
    if (t == 0)
      cell_step<0,1>(Wih, WhH, WhL, bia, nullptr, inph, inpl,
                     Hh + (size_t)rp*262144 + dir*1024,   // enc's final h (L3)
                     Hl + (size_t)rp*262144 + dir*1024,
                     Hh + (size_t)(rp^1)*262144 + dir*1024,
                     Hl + (size_t)(rp^1)*262144 + dir*1024,
                     creg, r0, n0, b0, LDS);
    else
      cell_step<0,0>(Wih, WhH, WhL, bia, nullptr, inph, inpl,
                     sH + dir*1024, sL + dir*1024,        // h from XCD scratch
                     Hh + (size_t)(rp^1)*262144 + dir*1024,
                     Hl + (size_t)(rp^1)*262144 + dir*1024,
                     creg, r0, n0, b0, LDS);
    bar(flagsD, 256, wg, (unsigned)(3*t + 2));
    xcopy_full(Hh + (size_t)(rp^1)*262144, Hl + (size_t)(rp^1)*262144,
               (ushort_t*)sH, (ushort_t*)sL, rank, nmem);
    xbar(xa, xf, nmem, (unsigned)(t + 1));
    mlp_gemm(sH, sL, mWh, mWl, Part, wg, LDS);
    bar(flagsD, 256, wg, (unsigned)(3*t + 3));
    if (wg < 128) mlp_combine(Part, mb, dout, inph, inpl, wg, t);
    bar(flagsD, 256, wg, (unsigned)(3*t + 4));
  }
}

// ---------------------------------------------------------------------------
// Prep kernels
// ---------------------------------------------------------------------------
__global__ void k_wplanes(ushort_t* Hp, ushort_t* Lp,
                          const float* Whh_f, const float* Whh_b)
{
  const size_t N = 2ull*4096*1024;
  for (size_t i = (size_t)blockIdx.x*blockDim.x + threadIdx.x; i < N;
       i += (size_t)gridDim.x*blockDim.x){
    int dir = (int)(i >> 22);
    int r   = (int)((i >> 10) & 4095);
    int k   = (int)(i & 1023);
    int n = r >> 2, q = r & 3;
    const float* W = dir ? Whh_b : Whh_f;
    float v = W[(size_t)(q*1024 + n)*1024 + k];
    unsigned short h = f2bf(v);
    Hp[i] = h;
    Lp[i] = f2bf(v - bf2f(h));
  }
}

__global__ void k_init(ushort_t* Hh, ushort_t* Hl,
                       ushort_t* inph, ushort_t* inpl,
                       ushort_t* mWh, ushort_t* mWl,
                       ushort_t* scrH, ushort_t* scrL,
                       const float* x, const float* mW, unsigned* cnt)
{
  const size_t N = 2097152;  // scr planes (8 XCD x 262144)
  for (size_t i = (size_t)blockIdx.x*blockDim.x + threadIdx.x; i < N;
       i += (size_t)gridDim.x*blockDim.x){
    scrH[i] = 0; scrL[i] = 0;
    if (i < 524288){
      Hh[i] = 0; Hl[i] = 0;
      float wv = mW[i];
      unsigned short wh = f2bf(wv);
      mWh[i] = wh;
      mWl[i] = f2bf(wv - bf2f(wh));
    }
    if (i < 32768){
      int b = (int)(i >> 8), d = (int)(i & 255);
      float v = x[((size_t)b*256 + 255)*256 + d];        // x[:, 255, :]
      unsigned short hi = f2bf(v);
      inph[i] = hi;
      inpl[i] = f2bf(v - bf2f(hi));
    }
    if (i < 2048) cnt[i] = 0;
  }
}

// ---------------------------------------------------------------------------
extern "C" void kernel_launch(void* const* d_in, const int* in_sizes, int n_in,
                              void* d_out, int out_size, void* d_ws, size_t ws_size,
                              hipStream_t stream)
{
  (void)in_sizes; (void)n_in; (void)out_size; (void)ws_size;
  const float* x      = (const float*)d_in[0];
  const float* eWih_f = (const float*)d_in[2];
  const float* eWhh_f = (const float*)d_in[3];
  const float* eb_f   = (const float*)d_in[4];
  const float* eWih_b = (const float*)d_in[5];
  const float* eWhh_b = (const float*)d_in[6];
  const float* eb_b   = (const float*)d_in[7];
  const float* dWih_f = (const float*)d_in[8];
  const float* dWhh_f = (const float*)d_in[9];
  const float* db_f   = (const float*)d_in[10];
  const float* dWih_b = (const float*)d_in[11];
  const float* dWhh_b = (const float*)d_in[12];
  const float* db_b   = (const float*)d_in[13];
  const float* mW     = (const float*)d_in[14];
  const float* mb     = (const float*)d_in[15];

  char* p = (char*)d_ws;
  size_t off = 0;
  unsigned* cnt   = (unsigned*)(p + off);  off += 8192;
  ushort_t* WhhEh = (ushort_t*)(p + off);  off += 16777216;
  ushort_t* WhhEl = (ushort_t*)(p + off);  off += 16777216;
  ushort_t* WhhDh = (ushort_t*)(p + off);  off += 16777216;
  ushort_t* WhhDl = (ushort_t*)(p + off);  off += 16777216;
  ushort_t* mWh   = (ushort_t*)(p + off);  off += 1048576;
  ushort_t* mWl   = (ushort_t*)(p + off);  off += 1048576;
  ushort_t* Hh    = (ushort_t*)(p + off);  off += 1048576;
  ushort_t* Hl    = (ushort_t*)(p + off);  off += 1048576;
  float*    C     = (float*)(p + off);     off += 1048576;
  ushort_t* inph  = (ushort_t*)(p + off);  off += 65536;
  ushort_t* inpl  = (ushort_t*)(p + off);  off += 65536;
  float*    Part  = (float*)(p + off);     off += 1048576;
  ushort_t* scrH  = (ushort_t*)(p + off);  off += 4194304;  // 8 XCD x 512KB
  ushort_t* scrL  = (ushort_t*)(p + off);  off += 4194304;

  unsigned* flagsD = cnt;              // 256
  unsigned* flagsE = cnt + 256;        // 256
  unsigned* eReg   = cnt + 512;        // 16 groups x 16
  unsigned* eArr   = cnt + 768;
  unsigned* eFlg   = cnt + 1024;
  unsigned* dReg   = cnt + 1280;       // 8 groups x 16
  unsigned* dArr   = cnt + 1408;
  unsigned* dFlg   = cnt + 1536;

  hipFuncSetAttribute(reinterpret_cast<const void*>(rnn_enc_kernel),
                      hipFuncAttributeMaxDynamicSharedMemorySize, 131072);
  hipFuncSetAttribute(reinterpret_cast<const void*>(rnn_dec_kernel),
                      hipFuncAttributeMaxDynamicSharedMemorySize, 131072);

  k_init   <<<512, 256, 0, stream>>>(Hh, Hl, inph, inpl, mWh, mWl,
                                     scrH, scrL, x, mW, cnt);
  k_wplanes<<<2048, 256, 0, stream>>>(WhhEh, WhhEl, eWhh_f, eWhh_b);
  k_wplanes<<<2048, 256, 0, stream>>>(WhhDh, WhhDl, dWhh_f, dWhh_b);

  rnn_enc_kernel<<<NWG, 256, 131072, stream>>>(eWih_f, eb_f, eWih_b, eb_b,
                                               WhhEh, WhhEl, x, Hh, Hl,
                                               scrH, scrL, C, flagsE,
                                               eReg, eArr, eFlg);
  rnn_dec_kernel<<<NWG, 256, 131072, stream>>>(dWih_f, db_f, dWih_b, db_b,
                                               WhhDh, WhhDl, mWh, mWl, mb,
                                               Hh, Hl, scrH, scrL, C,
                                               inph, inpl, Part,
                                               (float*)d_out, flagsD,
                                               dReg, dArr, dFlg);
}

// Round 9
// 10222.735 us; speedup vs baseline: 2.4348x; 2.4348x over previous
//
#include <hip/hip_runtime.h>
#include <stdint.h>

// ---------------------------------------------------------------------------
// SimpleRNN: bidirectional LSTM encoder (S=256) + autoregressive decoder (T=128)
// B=128, D=256, H=1024. Persistent kernels, fence-free flag grid barriers.
// R9: revert R8 mirror (HBM leak). R7 cell + (a) W-prefetch hidden under the
// barrier spin (bar_pf: raw s_barrier, waves0/1 issue next step's W chunks,
// wave3 spins), (b) decoder MLP as 32 single-WG tiles with in-WG K-split over
// 4 waves + LDS combine (no Part round-trip, 2 grid barriers/step not 3).
// 3-term split-bf16 MFMA (Wh*Ah + Wh*Al + Wl*Ah), f32 accum/gates.
// ---------------------------------------------------------------------------

typedef __attribute__((ext_vector_type(8))) short bfx8;
typedef __attribute__((ext_vector_type(4))) float f32x4;
typedef __attribute__((ext_vector_type(4))) unsigned short u16x4;
typedef unsigned short ushort_t;
typedef unsigned long long u64;

#define NWG 256
#define MFMA(a,b,c) __builtin_amdgcn_mfma_f32_16x16x32_bf16((a),(b),(c),0,0,0)
#define WAITVM(N) { asm volatile("s_waitcnt vmcnt(" #N ")" ::: "memory"); __builtin_amdgcn_sched_barrier(0); }
#define WAITLG(N) { asm volatile("s_waitcnt lgkmcnt(" #N ")" ::: "memory"); __builtin_amdgcn_sched_barrier(0); }
#define SBAR()    { __builtin_amdgcn_s_barrier(); __builtin_amdgcn_sched_barrier(0); }

__device__ __forceinline__ unsigned short f2bf(float f){
  unsigned u = __float_as_uint(f);
  u += 0x7FFFu + ((u >> 16) & 1u);          // round-to-nearest-even
  return (unsigned short)(u >> 16);
}
__device__ __forceinline__ float bf2f(unsigned short h){
  return __uint_as_float(((unsigned)h) << 16);
}
__device__ __forceinline__ float sigm(float x){ return 1.f/(1.f + __expf(-x)); }
__device__ __forceinline__ float tanh_(float x){ return 1.f - 2.f/(__expf(2.f*x) + 1.f); }

// plain (L1+L2 cached) async global->LDS: immutable weights
__device__ __forceinline__ void stage16(const void* g, void* l){
  __builtin_amdgcn_global_load_lds((const __attribute__((address_space(1))) void*)g,
                                   (__attribute__((address_space(3))) void*)l,
                                   16, 0, 0);
}
// agent-coherent (SC0|SC1 = 0x11, L3-served): mutable cross-XCD data
__device__ __forceinline__ void stage16c(const void* g, void* l){
  __builtin_amdgcn_global_load_lds((const __attribute__((address_space(1))) void*)g,
                                   (__attribute__((address_space(3))) void*)l,
                                   16, 0, 0x11);
}

// coherent 16B load (2 x u64 agent-relaxed atomics)
__device__ __forceinline__ bfx8 ld16c(const ushort_t* p){
  const u64* q = (const u64*)p;
  u64 a = __hip_atomic_load(q,     __ATOMIC_RELAXED, __HIP_MEMORY_SCOPE_AGENT);
  u64 b = __hip_atomic_load(q + 1, __ATOMIC_RELAXED, __HIP_MEMORY_SCOPE_AGENT);
  union { u64 u[2]; bfx8 v; } x; x.u[0] = a; x.u[1] = b; return x.v;
}
__device__ __forceinline__ void sth2(ushort_t* p, unsigned short v){
  __hip_atomic_store(p, v, __ATOMIC_RELAXED, __HIP_MEMORY_SCOPE_AGENT);
}

// two f32x4 (8 consecutive f32) -> hi/lo bf16 planes
__device__ __forceinline__ void cvt2(const f32x4& a, const f32x4& b, bfx8& hi, bfx8& lo){
#pragma unroll
  for (int j = 0; j < 4; ++j){
    unsigned short h0 = f2bf(a[j]);
    unsigned short h1 = f2bf(b[j]);
    hi[j]   = (short)h0; lo[j]   = (short)f2bf(a[j] - bf2f(h0));
    hi[4+j] = (short)h1; lo[4+j] = (short)f2bf(b[j] - bf2f(h1));
  }
}

// ---------------------------------------------------------------------------
// Plain fence-free grid barrier (wave0 scans). Used where no prefetch needed.
// ---------------------------------------------------------------------------
__device__ __forceinline__ void bar(unsigned* flags, int nflags, int me, unsigned gen){
  __syncthreads();                       // drains vmcnt(0): all stores done
  if (threadIdx.x == 0)
    __hip_atomic_store(&flags[me], gen, __ATOMIC_RELAXED, __HIP_MEMORY_SCOPE_AGENT);
  if (threadIdx.x < 64){
    const int l = threadIdx.x;
    for (;;){
      unsigned mn = 0xFFFFFFFFu;
      for (int o = l; o < nflags; o += 64){
        unsigned v = __hip_atomic_load(&flags[o], __ATOMIC_RELAXED, __HIP_MEMORY_SCOPE_AGENT);
        mn = mn < v ? mn : v;
      }
      if (__all((int)(mn >= gen))) break;
      __builtin_amdgcn_s_sleep(1);
    }
  }
  __syncthreads();
}

// ---------------------------------------------------------------------------
// Prefetching barrier: after the entry s_barrier, waves 0/1 issue next step's
// 3 W-chunks (ring bufs 0-2) while wave3 stores the flag and spin-scans.
// The W loads land during the spin -> hidden.
// ---------------------------------------------------------------------------
struct WPre {
  const ushort_t* pj[8];
  ushort_t* ldsb[3];
  bool active;                           // wv < 2
};
__device__ __forceinline__ void wpre_issue(const WPre& w){
  if (!w.active) return;
#pragma unroll
  for (int bp = 0; bp < 3; ++bp)
#pragma unroll
    for (int j = 0; j < 8; ++j)
      stage16(w.pj[j] + bp*64, w.ldsb[bp] + j*512);
}
__device__ __forceinline__ void bar_pf(unsigned* flags, int nflags, int me,
                                       unsigned gen, const WPre& w, bool pf){
  WAITLG(0); WAITVM(0);                  // own h-stores drained
  SBAR();                                // whole WG drained
  if (pf) wpre_issue(w);                 // waves 0/1: 24 W loads in flight
  if (threadIdx.x == 192)
    __hip_atomic_store(&flags[me], gen, __ATOMIC_RELAXED, __HIP_MEMORY_SCOPE_AGENT);
  if ((threadIdx.x >> 6) == 3){
    const int l = threadIdx.x & 63;
    for (;;){
      unsigned mn = 0xFFFFFFFFu;
      for (int o = l; o < nflags; o += 64){
        unsigned v = __hip_atomic_load(&flags[o], __ATOMIC_RELAXED, __HIP_MEMORY_SCOPE_AGENT);
        mn = mn < v ? mn : v;
      }
      if (__all((int)(mn >= gen))) break;
      __builtin_amdgcn_s_sleep(1);
    }
  }
  SBAR();
}

struct Frags { bfx8 awh0, awh1, awl0, awl1, bh0, bh1, bl0, bl1; };

// ---------------------------------------------------------------------------
// One LSTM cell step (R7-proven). Phase 1 (k<256): register-staged. Phase 2:
// depth-3 global_load_lds ring, counted vmcnt. W-chunks 4-6 are PRE-ISSUED
// by the caller (before the t-loop / inside bar_pf); prologue issues A only.
// LDS bytes: P1 4 planes @0/8K/16K/24K; ring buf bp @32K+bp*32K (4x8K planes).
// ---------------------------------------------------------------------------
template<int ENC>
__device__ __forceinline__ void cell_step(
    const float*    __restrict__ Wih,   // [4096][256] f32 original (this dir)
    const ushort_t* __restrict__ WhH,   // [4096][1024] bf16 hi (this dir)
    const ushort_t* __restrict__ WhL,   // lo
    const float*    __restrict__ bias,  // [4096] f32 (original order)
    const float*    __restrict__ xsl,   // ENC: x + tt*256 (row stride 65536)
    const ushort_t* __restrict__ iph,   // DEC: [128][256] hi
    const ushort_t* __restrict__ ipl,   // DEC: lo
    const ushort_t* __restrict__ hh,    // h hi source (+dir*1024), stride 2048
    const ushort_t* __restrict__ hl,    // h lo source
    ushort_t* __restrict__ outh, ushort_t* __restrict__ outl,
    float (&creg)[2][2],
    int r0, int n0, int b0, ushort_t* LDS)
{
  const int tid  = threadIdx.x;
  const int lane = tid & 63;
  const int wv   = tid >> 6;
  const int wm   = wv >> 1, wn = wv & 1;
  const int lr   = tid >> 3;               // phase-1 staging row 0..31
  const int lc   = tid & 7;
  const int cb   = lane >> 4;
  const int fr   = lane & 15;
  const int sc8  = lc ^ (lr & 7);          // phase-1 pre-swizzled source chunk
  const int sx   = fr & 7;
  const int rwa0 = wm*32 + fr, rwa1 = rwa0 + 16;
  const int rwb0 = wn*32 + fr, rwb1 = rwb0 + 16;

  // ---- phase-1 source pointers (rows r0+lr, r0+32+lr; gate-interleaved) ----
  const int ra = r0 + lr, rb = ra + 32;
  const float* wih0 = Wih + (size_t)((ra & 3)*1024 + (ra >> 2))*256 + sc8*8;
  const float* wih1 = Wih + (size_t)((rb & 3)*1024 + (rb >> 2))*256 + sc8*8;
  const float *xs0 = nullptr, *xs1 = nullptr;
  const ushort_t *ih0 = nullptr, *ih1 = nullptr, *il0 = nullptr, *il1 = nullptr;
  if (ENC){
    xs0 = xsl + (size_t)(b0 + lr)*65536 + sc8*8;
    xs1 = xs0 + (size_t)32*65536;
  } else {
    ih0 = iph + (size_t)(b0 + lr)*256 + sc8*8;  ih1 = ih0 + 32*256;
    il0 = ipl + (size_t)(b0 + lr)*256 + sc8*8;  il1 = il0 + 32*256;
  }

  // ---- phase-2 staging bases: wave wv stages plane wv ----
  const ushort_t* sb; size_t sstr; int srow0;
  if      (wv == 0){ sb = WhH; sstr = 1024; srow0 = r0; }
  else if (wv == 1){ sb = WhL; sstr = 1024; srow0 = r0; }
  else if (wv == 2){ sb = hh;  sstr = 2048; srow0 = b0; }
  else             { sb = hl;  sstr = 2048; srow0 = b0; }
  const int srw = lane >> 3;
  const int sg  = (lane & 7) ^ srw;        // swizzled source granule
  const ushort_t* pj[8];
#pragma unroll
  for (int j = 0; j < 8; ++j)
    pj[j] = sb + (size_t)(srow0 + j*8 + srw)*sstr + sg*8;
  ushort_t* ldsb[3];
#pragma unroll
  for (int bp = 0; bp < 3; ++bp)
    ldsb[bp] = LDS + 16384 + bp*16384 + wv*4096;

  auto ISSUE = [&](int c, int bp){
    const int ko = (c - 4)*64;
    if (wv < 2){
#pragma unroll
      for (int j = 0; j < 8; ++j)
        stage16(pj[j] + ko, ldsb[bp] + j*512);          // weights: L2-cached
    } else {
#pragma unroll
      for (int j = 0; j < 8; ++j)
        stage16c(pj[j] + ko, ldsb[bp] + j*512);         // h: agent-coherent
    }
  };

  f32x4 acc[2][2] = {};
  auto rdf = [&](const ushort_t* buf, int ks, Frags& f){
    const int ga = (((ks << 2) + cb) ^ sx) << 3;
    f.awh0 = *(const bfx8*)(buf +         rwa0*64 + ga);
    f.awh1 = *(const bfx8*)(buf +         rwa1*64 + ga);
    f.awl0 = *(const bfx8*)(buf + 4096  + rwa0*64 + ga);
    f.awl1 = *(const bfx8*)(buf + 4096  + rwa1*64 + ga);
    f.bh0  = *(const bfx8*)(buf + 8192  + rwb0*64 + ga);
    f.bh1  = *(const bfx8*)(buf + 8192  + rwb1*64 + ga);
    f.bl0  = *(const bfx8*)(buf + 12288 + rwb0*64 + ga);
    f.bl1  = *(const bfx8*)(buf + 12288 + rwb1*64 + ga);
  };
  auto mm12 = [&](const Frags& f){
    acc[0][0] = MFMA(f.awh0, f.bh0, acc[0][0]);
    acc[0][0] = MFMA(f.awh0, f.bl0, acc[0][0]);
    acc[0][0] = MFMA(f.awl0, f.bh0, acc[0][0]);
    acc[0][1] = MFMA(f.awh0, f.bh1, acc[0][1]);
    acc[0][1] = MFMA(f.awh0, f.bl1, acc[0][1]);
    acc[0][1] = MFMA(f.awl0, f.bh1, acc[0][1]);
    acc[1][0] = MFMA(f.awh1, f.bh0, acc[1][0]);
    acc[1][0] = MFMA(f.awh1, f.bl0, acc[1][0]);
    acc[1][0] = MFMA(f.awl1, f.bh0, acc[1][0]);
    acc[1][1] = MFMA(f.awh1, f.bh1, acc[1][1]);
    acc[1][1] = MFMA(f.awh1, f.bl1, acc[1][1]);
    acc[1][1] = MFMA(f.awl1, f.bh1, acc[1][1]);
  };

  // ---- phase-1 raw loads / cvt ----
  f32x4 rw0a, rw0b, rw1a, rw1b, rxa0, rxb0, rxa1, rxb1;
  bfx8 cwh0, cwh1, cwl0, cwl1, cah0, cah1, cal0, cal1;
  auto LOADRAW = [&](int kc){
    rw0a = *(const f32x4*)(wih0 + kc);  rw0b = *(const f32x4*)(wih0 + kc + 4);
    rw1a = *(const f32x4*)(wih1 + kc);  rw1b = *(const f32x4*)(wih1 + kc + 4);
    if (ENC){
      rxa0 = *(const f32x4*)(xs0 + kc); rxb0 = *(const f32x4*)(xs0 + kc + 4);
      rxa1 = *(const f32x4*)(xs1 + kc); rxb1 = *(const f32x4*)(xs1 + kc + 4);
    } else {
      cah0 = ld16c(ih0 + kc);  cah1 = ld16c(ih1 + kc);   // coherent inp
      cal0 = ld16c(il0 + kc);  cal1 = ld16c(il1 + kc);
    }
  };
  auto CVT = [&](){
    cvt2(rw0a, rw0b, cwh0, cwl0);
    cvt2(rw1a, rw1b, cwh1, cwl1);
    if (ENC){ cvt2(rxa0, rxb0, cah0, cal0); cvt2(rxa1, rxb1, cah1, cal1); }
  };

  LOADRAW(0);
  if (wv >= 2){ ISSUE(4, 0); ISSUE(5, 1); ISSUE(6, 2); }  // A prologue only
  CVT();                                                   // (W pre-issued)

  // ---- phase 1: chunks 0..3, register-staged into P1, raw barriers ----
  for (int c = 0; c < 4; ++c){
    *(bfx8*)(LDS +         lr    *64 + lc*8) = cwh0;
    *(bfx8*)(LDS +        (lr+32)*64 + lc*8) = cwh1;
    *(bfx8*)(LDS + 4096 +  lr    *64 + lc*8) = cwl0;
    *(bfx8*)(LDS + 4096 + (lr+32)*64 + lc*8) = cwl1;
    *(bfx8*)(LDS + 8192 +  lr    *64 + lc*8) = cah0;
    *(bfx8*)(LDS + 8192 + (lr+32)*64 + lc*8) = cah1;
    *(bfx8*)(LDS + 12288 + lr    *64 + lc*8) = cal0;
    *(bfx8*)(LDS + 12288 +(lr+32)*64 + lc*8) = cal1;
    WAITLG(0); SBAR();
    if (c < 3) LOADRAW((c + 1)*64);
    Frags f0, f1;
    rdf(LDS, 0, f0);
    rdf(LDS, 1, f1);
    WAITLG(8);
    mm12(f0);
    WAITLG(0); SBAR();
    if (c < 3) CVT();
    mm12(f1);
  }

  // ---- phase 2: chunks 4..19, depth-3 ring, counted vmcnt ----
  int bi = 0;
  for (int i = 4; i <= 19; ++i){
    if (i < 18)      { WAITVM(16); }
    else if (i == 18){ WAITVM(8); }
    else             { WAITVM(0); }
    SBAR();                                  // chunk i staged by all waves
    const ushort_t* buf = LDS + 16384 + bi*16384;
    Frags f0, f1;
    rdf(buf, 0, f0);
    rdf(buf, 1, f1);
    WAITLG(8);
    mm12(f0);
    WAITLG(0); SBAR();                       // all reads done -> buf free
    if (i <= 16) ISSUE(i + 3, bi);
    mm12(f1);
    bi = (bi == 2) ? 0 : bi + 1;
  }

  // ---- epilogue: gates -> c (regs), h -> global hi/lo planes (coherent) ----
#pragma unroll
  for (int m = 0; m < 2; ++m){
    const int n = n0 + wm*8 + m*4 + cb;
    const float bi_ = bias[n];
    const float bf_ = bias[1024 + n];
    const float bg_ = bias[2048 + n];
    const float bo_ = bias[3072 + n];
#pragma unroll
    for (int nb = 0; nb < 2; ++nb){
      const int b = b0 + wn*32 + nb*16 + fr;
      float gi = acc[m][nb][0] + bi_;
      float gf = acc[m][nb][1] + bf_;
      float gg = acc[m][nb][2] + bg_;
      float go = acc[m][nb][3] + bo_;
      float c_new = sigm(gf)*creg[m][nb] + sigm(gi)*tanh_(gg);
      float h_new = sigm(go)*tanh_(c_new);
      creg[m][nb] = c_new;
      unsigned short hi = f2bf(h_new);
      sth2(&outh[(size_t)b*2048 + n], hi);
      sth2(&outl[(size_t)b*2048 + n], f2bf(h_new - bf2f(hi)));
    }
  }
}

// ---------------------------------------------------------------------------
// Decoder MLP: 32 WGs, each one 32d x 32b tile; K=2048 split over the WG's 4
// waves (512 each, chunks of 32, wave-private depth-2 ring, swizzled LDS);
// LDS partial-combine; writes dout (plain) + inp planes (coherent).
// LDS: ring at byte 32768 + wv*16384 + (c&1)*8192; partials f32 at byte 0.
// ---------------------------------------------------------------------------
__device__ __forceinline__ void mlp32(
    const ushort_t* __restrict__ hch, const ushort_t* __restrict__ hcl,
    const ushort_t* __restrict__ mWh, const ushort_t* __restrict__ mWl,
    const float* __restrict__ mb, float* __restrict__ dout,
    ushort_t* __restrict__ inph, ushort_t* __restrict__ inpl,
    int wg, int t, ushort_t* LDS)
{
  const int tid = threadIdx.x, lane = tid & 63, wv = tid >> 6;
  const int d0 = (wg >> 2)*32, b0 = (wg & 3)*32;
  const int kb = wv*512;
  const int srw2 = lane >> 2;              // row within 16-row sub-block
  const int pg   = lane & 3;               // physical k-granule

  const ushort_t* base[4] = { mWh, mWl, hch, hcl };
  const int rb0[4] = { d0, d0, b0, b0 };
  const ushort_t* sp[8];
#pragma unroll
  for (int j = 0; j < 8; ++j){
    const int p = j >> 1, sub = j & 1;
    const int rl = sub*16 + srw2;
    const int sr = (rl ^ (rl >> 2)) & 3;
    sp[j] = base[p] + (size_t)(rb0[p] + rl)*2048 + kb + ((pg ^ sr)*8);
  }
  ushort_t* lb[2] = { LDS + 16384 + wv*8192, LDS + 16384 + wv*8192 + 4096 };

  auto MISSUE = [&](int c){
    ushort_t* B = lb[c & 1];
    const int ko = c*32;
#pragma unroll
    for (int j = 0; j < 8; ++j){
      const int p = j >> 1, sub = j & 1;
      if (p < 2) stage16 (sp[j] + ko, B + p*1024 + sub*512 + lane*8);
      else       stage16c(sp[j] + ko, B + p*1024 + sub*512 + lane*8);
    }
  };
  MISSUE(0); MISSUE(1);

  f32x4 acc[2][2] = {};
  const int lg = lane >> 4;                // logical k-granule
  for (int c = 0; c < 16; ++c){
    if (c < 15) { WAITVM(8); } else { WAITVM(0); }
    const ushort_t* B = lb[c & 1];
    bfx8 wf[2][2], af[2][2];
#pragma unroll
    for (int m = 0; m < 2; ++m){
      const int rl = m*16 + (lane & 15);
      const int sr = (rl ^ (rl >> 2)) & 3;
      const int off = rl*32 + ((lg ^ sr)*8);
      wf[0][m] = *(const bfx8*)(B + off);
      wf[1][m] = *(const bfx8*)(B + 1024 + off);
      af[0][m] = *(const bfx8*)(B + 2048 + off);
      af[1][m] = *(const bfx8*)(B + 3072 + off);
    }
    WAITLG(0);
    if (c < 14) MISSUE(c + 2);
#pragma unroll
    for (int m = 0; m < 2; ++m)
#pragma unroll
      for (int n = 0; n < 2; ++n){
        acc[m][n] = MFMA(wf[0][m], af[0][n], acc[m][n]);
        acc[m][n] = MFMA(wf[0][m], af[1][n], acc[m][n]);
        acc[m][n] = MFMA(wf[1][m], af[0][n], acc[m][n]);
      }
  }

  // partial combine via LDS (f32, 16 KB at byte 0)
  float* PL = (float*)LDS;
#pragma unroll
  for (int m = 0; m < 2; ++m)
#pragma unroll
    for (int n = 0; n < 2; ++n)
#pragma unroll
      for (int r = 0; r < 4; ++r)
        PL[wv*1024 + (m*2 + n)*256 + r*64 + lane] = acc[m][n][r];
  __syncthreads();
  for (int o = tid; o < 1024; o += 256){
    float s = PL[o] + PL[1024 + o] + PL[2048 + o] + PL[3072 + o];
    const int m = o >> 9, n = (o >> 8) & 1, r = (o >> 6) & 3, l = o & 63;
    const int d = d0 + m*16 + (l >> 4)*4 + r;
    const int b = b0 + n*16 + (l & 15);
    s += mb[d];
    dout[((size_t)b*128 + t)*256 + d] = s;
    const unsigned short hv = f2bf(s);
    sth2(&inph[(size_t)b*256 + d], hv);
    sth2(&inpl[(size_t)b*256 + d], f2bf(s - bf2f(hv)));
  }
}

// WG -> (dir, rowgroup, b-half); b-halves 8 apart => XCD co-location.
__device__ __forceinline__ void wg_decode(int wg, int& dir, int& r0, int& n0,
                                          int& b0, int& me){
  const int half = (wg >> 3) & 1;
  const int rgd  = (wg & 7) | ((wg >> 4) << 3);        // 0..127
  dir = rgd >> 6;
  const int rg = rgd & 63;
  r0 = rg * 64; n0 = rg * 16; b0 = half * 64;
  me = (rg << 1) | half;                               // 0..127 within dir
}

// Build the W-prefetch descriptor (chunks 4-6 into ring bufs 0-2).
__device__ __forceinline__ WPre make_wpre(const ushort_t* WhH, const ushort_t* WhL,
                                          int r0, ushort_t* LDS){
  const int tid = threadIdx.x, lane = tid & 63, wv = tid >> 6;
  const int srw = lane >> 3;
  const int sg  = (lane & 7) ^ srw;
  WPre w;
  w.active = (wv < 2);
  const ushort_t* sb = (wv == 1) ? WhL : WhH;
#pragma unroll
  for (int j = 0; j < 8; ++j)
    w.pj[j] = sb + (size_t)(r0 + j*8 + srw)*1024 + sg*8;
#pragma unroll
  for (int bp = 0; bp < 3; ++bp)
    w.ldsb[bp] = LDS + 16384 + bp*16384 + wv*4096;
  return w;
}

__global__ void __launch_bounds__(256) rnn_enc_kernel(
    const float* __restrict__ Wih_f, const float* __restrict__ b_f,
    const float* __restrict__ Wih_b, const float* __restrict__ b_b,
    const ushort_t* __restrict__ WhhH, const ushort_t* __restrict__ WhhL,
    const float* __restrict__ x,
    ushort_t* __restrict__ Hh, ushort_t* __restrict__ Hl,
    float* __restrict__ C, unsigned* flagsE)
{
  extern __shared__ ushort_t LDS[];
  int dir, r0, n0, b0, me;
  wg_decode(blockIdx.x, dir, r0, n0, b0, me);
  const float* Wih = dir ? Wih_b : Wih_f;
  const float* bia = dir ? b_b : b_f;
  const ushort_t* WhH = WhhH + (size_t)dir*4096*1024;
  const ushort_t* WhL = WhhL + (size_t)dir*4096*1024;
  unsigned* fl = flagsE + dir*128;
  const WPre wp = make_wpre(WhH, WhL, r0, LDS);

  float creg[2][2] = {{0.f, 0.f}, {0.f, 0.f}};
  wpre_issue(wp);                           // t=0 W prologue
  for (int t = 0; t < 256; ++t){
    const int tt = dir ? (255 - t) : t;
    const int rp = t & 1;
    cell_step<1>(Wih, WhH, WhL, bia,
                 x + (size_t)tt*256, nullptr, nullptr,
                 Hh + (size_t)rp     *262144 + dir*1024,
                 Hl + (size_t)rp     *262144 + dir*1024,
                 Hh + (size_t)(rp^1) *262144 + dir*1024,
                 Hl + (size_t)(rp^1) *262144 + dir*1024,
                 creg, r0, n0, b0, LDS);
    bar_pf(fl, 128, me, (unsigned)(t + 1), wp, t < 255);
  }
  // hand off c-state to decoder (cross-kernel boundary flushes)
  {
    const int lane = threadIdx.x & 63, wv = threadIdx.x >> 6;
    const int wm = wv >> 1, wn = wv & 1, cb = lane >> 4, fr = lane & 15;
    float* Cst = C + (size_t)dir*1024*128;
#pragma unroll
    for (int m = 0; m < 2; ++m)
#pragma unroll
      for (int nb = 0; nb < 2; ++nb){
        const int n = n0 + wm*8 + m*4 + cb;
        const int b = b0 + wn*32 + nb*16 + fr;
        Cst[n*128 + b] = creg[m][nb];
      }
  }
}

__global__ void __launch_bounds__(256) rnn_dec_kernel(
    const float* __restrict__ Wih_f, const float* __restrict__ b_f,
    const float* __restrict__ Wih_b, const float* __restrict__ b_b,
    const ushort_t* __restrict__ WhhH, const ushort_t* __restrict__ WhhL,
    const ushort_t* __restrict__ mWh, const ushort_t* __restrict__ mWl,
    const float* __restrict__ mb,
    ushort_t* __restrict__ Hh, ushort_t* __restrict__ Hl,
    float* __restrict__ C,
    ushort_t* __restrict__ inph, ushort_t* __restrict__ inpl,
    float* __restrict__ dout, unsigned* flagsD)
{
  extern __shared__ ushort_t LDS[];
  const int wg = blockIdx.x;
  int dir, r0, n0, b0, me;
  wg_decode(wg, dir, r0, n0, b0, me);
  const float* Wih = dir ? Wih_b : Wih_f;
  const float* bia = dir ? b_b : b_f;
  const ushort_t* WhH = WhhH + (size_t)dir*4096*1024;
  const ushort_t* WhL = WhhL + (size_t)dir*4096*1024;
  const WPre wp = make_wpre(WhH, WhL, r0, LDS);

  float creg[2][2];
  {
    const int lane = threadIdx.x & 63, wv = threadIdx.x >> 6;
    const int wm = wv >> 1, wn = wv & 1, cb = lane >> 4, fr = lane & 15;
    const float* Cst = C + (size_t)dir*1024*128;
#pragma unroll
    for (int m = 0; m < 2; ++m)
#pragma unroll
      for (int nb = 0; nb < 2; ++nb){
        const int n = n0 + wm*8 + m*4 + cb;
        const int b = b0 + wn*32 + nb*16 + fr;
        creg[m][nb] = Cst[n*128 + b];
      }
  }
  wpre_issue(wp);                           // t=0 W prologue
  for (int t = 0; t < 128; ++t){
    const int rp = t & 1;
    cell_step<0>(Wih, WhH, WhL, bia,
                 nullptr, inph, inpl,
                 Hh + (size_t)rp     *262144 + dir*1024,
                 Hl + (size_t)rp     *262144 + dir*1024,
                 Hh + (size_t)(rp^1) *262144 + dir*1024,
                 Hl + (size_t)(rp^1) *262144 + dir*1024,
                 creg, r0, n0, b0, LDS);
    bar(flagsD, 256, wg, (unsigned)(2*t + 1));
    if (wg < 32)
      mlp32(Hh + (size_t)(rp^1)*262144, Hl + (size_t)(rp^1)*262144,
            mWh, mWl, mb, dout, inph, inpl, wg, t, LDS);
    bar_pf(flagsD, 256, wg, (unsigned)(2*t + 2), wp, t < 127);
  }
}

// ---------------------------------------------------------------------------
// Prep kernels
// ---------------------------------------------------------------------------
__global__ void k_wplanes(ushort_t* Hp, ushort_t* Lp,
                          const float* Whh_f, const float* Whh_b)
{
  const size_t N = 2ull*4096*1024;
  for (size_t i = (size_t)blockIdx.x*blockDim.x + threadIdx.x; i < N;
       i += (size_t)gridDim.x*blockDim.x){
    int dir = (int)(i >> 22);
    int r   = (int)((i >> 10) & 4095);
    int k   = (int)(i & 1023);
    int n = r >> 2, q = r & 3;
    const float* W = dir ? Whh_b : Whh_f;
    float v = W[(size_t)(q*1024 + n)*1024 + k];
    unsigned short h = f2bf(v);
    Hp[i] = h;
    Lp[i] = f2bf(v - bf2f(h));
  }
}

__global__ void k_init(ushort_t* Hh, ushort_t* Hl,
                       ushort_t* inph, ushort_t* inpl,
                       ushort_t* mWh, ushort_t* mWl,
                       const float* x, const float* mW, unsigned* cnt)
{
  const size_t N = 524288;  // 2 parity * 128 * 2048 == 256*2048 (mlp)
  for (size_t i = (size_t)blockIdx.x*blockDim.x + threadIdx.x; i < N;
       i += (size_t)gridDim.x*blockDim.x){
    Hh[i] = 0; Hl[i] = 0;
    float wv = mW[i];
    unsigned short wh = f2bf(wv);
    mWh[i] = wh;
    mWl[i] = f2bf(wv - bf2f(wh));
    if (i < 32768){
      int b = (int)(i >> 8), d = (int)(i & 255);
      float v = x[((size_t)b*256 + 255)*256 + d];        // x[:, 255, :]
      unsigned short hi = f2bf(v);
      inph[i] = hi;
      inpl[i] = f2bf(v - bf2f(hi));
    }
    if (i < 2048) cnt[i] = 0;
  }
}

// ---------------------------------------------------------------------------
extern "C" void kernel_launch(void* const* d_in, const int* in_sizes, int n_in,
                              void* d_out, int out_size, void* d_ws, size_t ws_size,
                              hipStream_t stream)
{
  (void)in_sizes; (void)n_in; (void)out_size; (void)ws_size;
  const float* x      = (const float*)d_in[0];
  const float* eWih_f = (const float*)d_in[2];
  const float* eWhh_f = (const float*)d_in[3];
  const float* eb_f   = (const float*)d_in[4];
  const float* eWih_b = (const float*)d_in[5];
  const float* eWhh_b = (const float*)d_in[6];
  const float* eb_b   = (const float*)d_in[7];
  const float* dWih_f = (const float*)d_in[8];
  const float* dWhh_f = (const float*)d_in[9];
  const float* db_f   = (const float*)d_in[10];
  const float* dWih_b = (const float*)d_in[11];
  const float* dWhh_b = (const float*)d_in[12];
  const float* db_b   = (const float*)d_in[13];
  const float* mW     = (const float*)d_in[14];
  const float* mb     = (const float*)d_in[15];

  char* p = (char*)d_ws;
  size_t off = 0;
  unsigned* cnt   = (unsigned*)(p + off);  off += 8192;
  ushort_t* WhhEh = (ushort_t*)(p + off);  off += 16777216;
  ushort_t* WhhEl = (ushort_t*)(p + off);  off += 16777216;
  ushort_t* WhhDh = (ushort_t*)(p + off);  off += 16777216;
  ushort_t* WhhDl = (ushort_t*)(p + off);  off += 16777216;
  ushort_t* mWh   = (ushort_t*)(p + off);  off += 1048576;
  ushort_t* mWl   = (ushort_t*)(p + off);  off += 1048576;
  ushort_t* Hh    = (ushort_t*)(p + off);  off += 1048576;
  ushort_t* Hl    = (ushort_t*)(p + off);  off += 1048576;
  float*    C     = (float*)(p + off);     off += 1048576;
  ushort_t* inph  = (ushort_t*)(p + off);  off += 65536;
  ushort_t* inpl  = (ushort_t*)(p + off);  off += 65536;

  unsigned* flagsD = cnt;              // 256
  unsigned* flagsE = cnt + 256;        // 2 x 128

  hipFuncSetAttribute(reinterpret_cast<const void*>(rnn_enc_kernel),
                      hipFuncAttributeMaxDynamicSharedMemorySize, 131072);
  hipFuncSetAttribute(reinterpret_cast<const void*>(rnn_dec_kernel),
                      hipFuncAttributeMaxDynamicSharedMemorySize, 131072);

  k_init   <<<512, 256, 0, stream>>>(Hh, Hl, inph, inpl, mWh, mWl, x, mW, cnt);
  k_wplanes<<<2048, 256, 0, stream>>>(WhhEh, WhhEl, eWhh_f, eWhh_b);
  k_wplanes<<<2048, 256, 0, stream>>>(WhhDh, WhhDl, dWhh_f, dWhh_b);

  rnn_enc_kernel<<<NWG, 256, 131072, stream>>>(eWih_f, eb_f, eWih_b, eb_b,
                                               WhhEh, WhhEl, x, Hh, Hl, C, flagsE);
  rnn_dec_kernel<<<NWG, 256, 131072, stream>>>(dWih_f, db_f, dWih_b, db_b,
                                               WhhDh, WhhDl, mWh, mWl, mb,
                                               Hh, Hl, C, inph, inpl,
                                               (float*)d_out, flagsD);
}